// Round 1
// baseline (713.355 us; speedup 1.0000x reference)
//
#include <hip/hip_runtime.h>
#include <hip/hip_fp16.h>
#include <math.h>

#define ITERS 12

typedef __attribute__((ext_vector_type(8))) short short8;
typedef __attribute__((ext_vector_type(4))) float float4v;

static __device__ inline unsigned short f2bf(float f) {
    union { float f; unsigned int u; } c; c.f = f;
    unsigned int u = c.u;
    u += 0x7fffu + ((u >> 16) & 1u);          // round-to-nearest-even
    return (unsigned short)(u >> 16);
}
static __device__ inline float bf2f(unsigned short h) {
    union { float f; unsigned int u; } c; c.u = ((unsigned int)h) << 16;
    return c.f;
}

// ---------------------------------------------------------------------------
// Kernel A (unchanged): P = l2_normalize(X @ W^T + b), emitted as split-bf16
// rows of 192:
//   sub:  [hi(64) | lo(64) | hi(64)]
//   edge: [hi(64) | hi(64) | lo(64)]
// so that subE @ edgeE^T over K=192 = Ah*Bh + Al*Bh + Ah*Bl (lo*lo dropped).
// ---------------------------------------------------------------------------
__global__ __launch_bounds__(256) void proj_norm_kernel(
    const float* __restrict__ Xsub, const float* __restrict__ Xedge,
    const float* __restrict__ Wsub, const float* __restrict__ bsub,
    const float* __restrict__ Wedge, const float* __restrict__ bedge,
    unsigned short* __restrict__ subE, unsigned short* __restrict__ edgeE)
{
    const int mat = blockIdx.y;
    const float* X  = mat ? Xedge : Xsub;
    const float* W  = mat ? Wedge : Wsub;
    const float* Bv = mat ? bedge : bsub;
    unsigned short* OUT = mat ? edgeE : subE;

    const int r0 = blockIdx.x * 32;
    const int t  = threadIdx.x;
    const int tx = t & 15, ty = t >> 4;

    __shared__ float xs[64 * 34];   // [k][row(32)+pad]
    __shared__ float ws[64 * 68];   // [k][col(64)+pad]

    float acc[2][4] = {};

    for (int ch = 0; ch < 8; ++ch) {
        const int kb = ch * 64;
#pragma unroll
        for (int i = 0; i < 2; ++i) {
            int e = t + 256 * i;            // 512 float4 (32 rows x 16 kq)
            int row = e & 31, kq = e >> 5;
            float4 xv = *(const float4*)(X + (size_t)(r0 + row) * 512 + kb + kq * 4);
            xs[(kq * 4 + 0) * 34 + row] = xv.x;
            xs[(kq * 4 + 1) * 34 + row] = xv.y;
            xs[(kq * 4 + 2) * 34 + row] = xv.z;
            xs[(kq * 4 + 3) * 34 + row] = xv.w;
        }
#pragma unroll
        for (int i = 0; i < 4; ++i) {
            int e = t + 256 * i;            // 1024 float4 (64 cols x 16 kq)
            int col = e & 63, kq = e >> 6;
            float4 wv = *(const float4*)(W + (size_t)col * 512 + kb + kq * 4);
            ws[(kq * 4 + 0) * 68 + col] = wv.x;
            ws[(kq * 4 + 1) * 68 + col] = wv.y;
            ws[(kq * 4 + 2) * 68 + col] = wv.z;
            ws[(kq * 4 + 3) * 68 + col] = wv.w;
        }
        __syncthreads();
#pragma unroll 8
        for (int k = 0; k < 64; ++k) {
            const float2 a2 = *(const float2*)&xs[k * 34 + ty * 2];
            const float4 b4 = *(const float4*)&ws[k * 68 + tx * 4];
            acc[0][0] = fmaf(a2.x, b4.x, acc[0][0]);
            acc[0][1] = fmaf(a2.x, b4.y, acc[0][1]);
            acc[0][2] = fmaf(a2.x, b4.z, acc[0][2]);
            acc[0][3] = fmaf(a2.x, b4.w, acc[0][3]);
            acc[1][0] = fmaf(a2.y, b4.x, acc[1][0]);
            acc[1][1] = fmaf(a2.y, b4.y, acc[1][1]);
            acc[1][2] = fmaf(a2.y, b4.z, acc[1][2]);
            acc[1][3] = fmaf(a2.y, b4.w, acc[1][3]);
        }
        __syncthreads();
    }

    const float4 bb = *(const float4*)(Bv + tx * 4);
#pragma unroll
    for (int i = 0; i < 2; ++i) {
        acc[i][0] += bb.x; acc[i][1] += bb.y; acc[i][2] += bb.z; acc[i][3] += bb.w;
        float s = acc[i][0]*acc[i][0] + acc[i][1]*acc[i][1]
                + acc[i][2]*acc[i][2] + acc[i][3]*acc[i][3];
#pragma unroll
        for (int off = 1; off <= 8; off <<= 1)
            s += __shfl_xor(s, off, 64);
        const float inv = 1.0f / fmaxf(sqrtf(s), 1e-12f);

        unsigned short h[4], l[4];
#pragma unroll
        for (int j = 0; j < 4; ++j) {
            const float v = acc[i][j] * inv;
            h[j] = f2bf(v);
            l[j] = f2bf(v - bf2f(h[j]));
        }
        uint2 hp, lp;
        hp.x = (unsigned)h[0] | ((unsigned)h[1] << 16);
        hp.y = (unsigned)h[2] | ((unsigned)h[3] << 16);
        lp.x = (unsigned)l[0] | ((unsigned)l[1] << 16);
        lp.y = (unsigned)l[2] | ((unsigned)l[3] << 16);

        unsigned short* base = OUT + (size_t)(r0 + ty * 2 + i) * 192 + tx * 4;
        *(uint2*)(base)       = hp;
        *(uint2*)(base + 64)  = mat ? hp : lp;   // edge: hi ; sub: lo
        *(uint2*)(base + 128) = mat ? lp : hp;   // edge: lo ; sub: hi
    }
}

// ---------------------------------------------------------------------------
// Kernel F: FUSED scores + entmax.  One block = 16 sub-rows x all 8192 edges.
// 512 threads (8 waves); wave w owns cols [1024w, 1024w+1024) = 64 MFMA
// n-tiles, processed in pairs.  Scores kept in registers as packed fp16
// (zh[128] = 128 VGPR); fp16 quantization via __float2half_rn matches the
// old z-buffer numerics exactly.  No LDS staging for the GEMM: A fragments
// (16x192) load once per wave, B fragments stream from L2 (edgeE = 3.1 MB,
// fits one XCD L2).  MFMA C-layout: row = quad*4+reg, col = li  ->  each
// lane owns rows {4q..4q+3} of the block, 2 cols per zh word (cols tp*32+li
// and tp*32+16+li).  Entmax support-iteration reduces per-quad via shfl_xor
// (16 lanes == one quad hold a row's col-slice) then across 8 waves via a
// tiny LDS table.  Out stores are nontemporal so the 268 MB write stream
// doesn't evict edgeE from L2.
// __launch_bounds__(512, 2): 2 waves/EU -> compiler caps VGPR at 256 so the
// 8-wave block is launchable (1 block/CU).
// ---------------------------------------------------------------------------
__global__ __launch_bounds__(512, 2) void fused_score_entmax_kernel(
    const unsigned short* __restrict__ subE,
    const unsigned short* __restrict__ edgeE,
    const float* __restrict__ log_scale,
    float* __restrict__ out)
{
    const int t    = threadIdx.x;
    const int lane = t & 63;
    const int wid  = t >> 6;
    const int li   = lane & 15;
    const int quad = lane >> 4;
    const int r0   = blockIdx.x * 16;
    const int c0   = wid * 1024;

    __shared__ float redS[8][16][4];   // [wave][row][{n,s1,s2,pad}]
    __shared__ float tauS[16];
    __shared__ int   convS;

    // ---- A fragments: 16 rows x K=192 (all waves load the same 6 KB) ----
    short8 af[6];
#pragma unroll
    for (int kk = 0; kk < 6; ++kk)
        af[kk] = *(const short8*)(subE + (size_t)(r0 + li) * 192 + kk * 32 + quad * 8);

    float sc = expf(log_scale[0]);
    sc = fminf(fmaxf(sc, 0.5f), 20.0f);
    const float zs = sc * 0.5f;        // z = scores/2

    // ---- GEMM phase: 64 n-tiles per wave, in pairs; scores -> packed fp16 ----
    unsigned int zh[128];              // zh[tp*4+r]: row 4*quad+r, cols tp*32+li / +16

#pragma unroll
    for (int tp = 0; tp < 32; ++tp) {
        const unsigned short* b0p = edgeE + (size_t)(c0 + tp * 32 + li) * 192 + quad * 8;
        const unsigned short* b1p = b0p + (size_t)16 * 192;
        float4v a0 = (float4v){0.f, 0.f, 0.f, 0.f};
        float4v a1 = (float4v){0.f, 0.f, 0.f, 0.f};
#pragma unroll
        for (int kk = 0; kk < 6; ++kk) {
            short8 b0 = *(const short8*)(b0p + kk * 32);
            a0 = __builtin_amdgcn_mfma_f32_16x16x32_bf16(af[kk], b0, a0, 0, 0, 0);
        }
#pragma unroll
        for (int kk = 0; kk < 6; ++kk) {
            short8 b1 = *(const short8*)(b1p + kk * 32);
            a1 = __builtin_amdgcn_mfma_f32_16x16x32_bf16(af[kk], b1, a1, 0, 0, 0);
        }
#pragma unroll
        for (int r = 0; r < 4; ++r) {
            union { unsigned u; __half2 h2; } cv;
            cv.h2.x = __float2half_rn(a0[r] * zs);
            cv.h2.y = __float2half_rn(a1[r] * zs);
            zh[tp * 4 + r] = cv.u;
        }
    }

    // ---- row max -> tau0 = m - 1 (tau* is always in [m-1, m)) ----
    float mx[4];
#pragma unroll
    for (int r = 0; r < 4; ++r) mx[r] = -1e30f;
#pragma unroll
    for (int j = 0; j < 128; ++j) {
        union { unsigned u; __half2 h2; } cv; cv.u = zh[j];
        float2 f = __half22float2(cv.h2);
        mx[j & 3] = fmaxf(mx[j & 3], fmaxf(f.x, f.y));
    }
#pragma unroll
    for (int off = 1; off <= 8; off <<= 1)
#pragma unroll
        for (int r = 0; r < 4; ++r)
            mx[r] = fmaxf(mx[r], __shfl_xor(mx[r], off, 64));
    if (li == 0) {
#pragma unroll
        for (int r = 0; r < 4; ++r) redS[wid][quad * 4 + r][0] = mx[r];
    }
    __syncthreads();
    if (t < 16) {
        float m = redS[0][t][0];
#pragma unroll
        for (int w = 1; w < 8; ++w) m = fmaxf(m, redS[w][t][0]);
        tauS[t] = m - 1.0f;
    }
    __syncthreads();
    float tau[4];
#pragma unroll
    for (int r = 0; r < 4; ++r) tau[r] = tauS[quad * 4 + r];

    // ---- support-set iteration with exact quadratic solve ----
    for (int it = 0; it < ITERS; ++it) {
        float n[4]  = {0.f, 0.f, 0.f, 0.f};
        float s1[4] = {0.f, 0.f, 0.f, 0.f};
        float s2[4] = {0.f, 0.f, 0.f, 0.f};
#pragma unroll
        for (int j = 0; j < 128; ++j) {
            union { unsigned u; __half2 h2; } cv; cv.u = zh[j];
            float2 f = __half22float2(cv.h2);
            const int r = j & 3;
            {
                const bool  p  = f.x > tau[r];
                const float zm = p ? f.x : 0.f;
                n[r]  += p ? 1.f : 0.f;
                s1[r] += zm;
                s2[r]  = fmaf(zm, f.x, s2[r]);
            }
            {
                const bool  p  = f.y > tau[r];
                const float zm = p ? f.y : 0.f;
                n[r]  += p ? 1.f : 0.f;
                s1[r] += zm;
                s2[r]  = fmaf(zm, f.y, s2[r]);
            }
        }
#pragma unroll
        for (int off = 1; off <= 8; off <<= 1)
#pragma unroll
            for (int r = 0; r < 4; ++r) {
                n[r]  += __shfl_xor(n[r],  off, 64);
                s1[r] += __shfl_xor(s1[r], off, 64);
                s2[r] += __shfl_xor(s2[r], off, 64);
            }
        if (li == 0) {
#pragma unroll
            for (int r = 0; r < 4; ++r) {
                redS[wid][quad * 4 + r][0] = n[r];
                redS[wid][quad * 4 + r][1] = s1[r];
                redS[wid][quad * 4 + r][2] = s2[r];
            }
        }
        __syncthreads();

        bool cf = true;
        if (t < 16) {
            float N = 0.f, S1 = 0.f, S2 = 0.f;
#pragma unroll
            for (int w = 0; w < 8; ++w) {
                N  += redS[w][t][0];
                S1 += redS[w][t][1];
                S2 += redS[w][t][2];
            }
            const float told = tauS[t];
            const float disc = S1 * S1 - N * (S2 - 1.0f);
            float tn;
            if (disc >= 0.0f) {
                tn = (S1 - sqrtf(disc)) / N;
            } else {
                const float g = S1 - N * told;
                const float f = S2 - told * (2.0f * S1 - N * told);
                tn = told + (f - 1.0f) / (2.0f * g);
            }
            cf = (tn == told);
            tauS[t] = tn;
        }
        if (wid == 0) {
            unsigned long long bm = __ballot(cf);
            if (lane == 0) convS = (bm == ~0ull) ? 1 : 0;
        }
        __syncthreads();
#pragma unroll
        for (int r = 0; r < 4; ++r) tau[r] = tauS[quad * 4 + r];
        if (convS) break;
    }

    // ---- emit p = clip(z - tau, 0)^2, nontemporal (don't pollute L2) ----
    float* orow[4];
#pragma unroll
    for (int r = 0; r < 4; ++r)
        orow[r] = out + (size_t)(r0 + quad * 4 + r) * 8192 + c0 + li;
#pragma unroll
    for (int tp = 0; tp < 32; ++tp)
#pragma unroll
        for (int r = 0; r < 4; ++r) {
            union { unsigned u; __half2 h2; } cv; cv.u = zh[tp * 4 + r];
            float2 f = __half22float2(cv.h2);
            float d0 = fmaxf(f.x - tau[r], 0.f);
            float d1 = fmaxf(f.y - tau[r], 0.f);
            __builtin_nontemporal_store(d0 * d0, orow[r] + tp * 32);
            __builtin_nontemporal_store(d1 * d1, orow[r] + tp * 32 + 16);
        }
}

// ---------------------------------------------------------------------------
extern "C" void kernel_launch(void* const* d_in, const int* in_sizes, int n_in,
                              void* d_out, int out_size, void* d_ws, size_t ws_size,
                              hipStream_t stream)
{
    const float* edge_repr = (const float*)d_in[0];
    const float* sub_repr  = (const float*)d_in[1];
    const float* W_sub     = (const float*)d_in[2];
    const float* b_sub     = (const float*)d_in[3];
    const float* W_edge    = (const float*)d_in[4];
    const float* b_edge    = (const float*)d_in[5];
    const float* log_scale = (const float*)d_in[6];
    float* out = (float*)d_out;

    unsigned short* subE  = (unsigned short*)d_ws;                 // 3 MB
    unsigned short* edgeE = subE + (size_t)8192 * 192;             // 3 MB

    proj_norm_kernel<<<dim3(256, 2), 256, 0, stream>>>(
        sub_repr, edge_repr, W_sub, b_sub, W_edge, b_edge, subE, edgeE);

    fused_score_entmax_kernel<<<dim3(512), 512, 0, stream>>>(
        subE, edgeE, log_scale, out);
}

// Round 3
// 710.785 us; speedup vs baseline: 1.0036x; 1.0036x over previous
//
#include <hip/hip_runtime.h>
#include <hip/hip_fp16.h>
#include <math.h>

#define ITERS 12

typedef __attribute__((ext_vector_type(8))) short short8;
typedef __attribute__((ext_vector_type(4))) float float4v;

static __device__ inline unsigned short f2bf(float f) {
    union { float f; unsigned int u; } c; c.f = f;
    unsigned int u = c.u;
    u += 0x7fffu + ((u >> 16) & 1u);          // round-to-nearest-even
    return (unsigned short)(u >> 16);
}
static __device__ inline float bf2f(unsigned short h) {
    union { float f; unsigned int u; } c; c.u = ((unsigned int)h) << 16;
    return c.f;
}

// ---------------------------------------------------------------------------
// Kernel A (unchanged): P = l2_normalize(X @ W^T + b), emitted as split-bf16
// rows of 192:
//   sub:  [hi(64) | lo(64) | hi(64)]
//   edge: [hi(64) | hi(64) | lo(64)]
// so that subE @ edgeE^T over K=192 = Ah*Bh + Al*Bh + Ah*Bl (lo*lo dropped).
// ---------------------------------------------------------------------------
__global__ __launch_bounds__(256) void proj_norm_kernel(
    const float* __restrict__ Xsub, const float* __restrict__ Xedge,
    const float* __restrict__ Wsub, const float* __restrict__ bsub,
    const float* __restrict__ Wedge, const float* __restrict__ bedge,
    unsigned short* __restrict__ subE, unsigned short* __restrict__ edgeE)
{
    const int mat = blockIdx.y;
    const float* X  = mat ? Xedge : Xsub;
    const float* W  = mat ? Wedge : Wsub;
    const float* Bv = mat ? bedge : bsub;
    unsigned short* OUT = mat ? edgeE : subE;

    const int r0 = blockIdx.x * 32;
    const int t  = threadIdx.x;
    const int tx = t & 15, ty = t >> 4;

    __shared__ float xs[64 * 34];   // [k][row(32)+pad]
    __shared__ float ws[64 * 68];   // [k][col(64)+pad]

    float acc[2][4] = {};

    for (int ch = 0; ch < 8; ++ch) {
        const int kb = ch * 64;
#pragma unroll
        for (int i = 0; i < 2; ++i) {
            int e = t + 256 * i;            // 512 float4 (32 rows x 16 kq)
            int row = e & 31, kq = e >> 5;
            float4 xv = *(const float4*)(X + (size_t)(r0 + row) * 512 + kb + kq * 4);
            xs[(kq * 4 + 0) * 34 + row] = xv.x;
            xs[(kq * 4 + 1) * 34 + row] = xv.y;
            xs[(kq * 4 + 2) * 34 + row] = xv.z;
            xs[(kq * 4 + 3) * 34 + row] = xv.w;
        }
#pragma unroll
        for (int i = 0; i < 4; ++i) {
            int e = t + 256 * i;            // 1024 float4 (64 cols x 16 kq)
            int col = e & 63, kq = e >> 6;
            float4 wv = *(const float4*)(W + (size_t)col * 512 + kb + kq * 4);
            ws[(kq * 4 + 0) * 68 + col] = wv.x;
            ws[(kq * 4 + 1) * 68 + col] = wv.y;
            ws[(kq * 4 + 2) * 68 + col] = wv.z;
            ws[(kq * 4 + 3) * 68 + col] = wv.w;
        }
        __syncthreads();
#pragma unroll 8
        for (int k = 0; k < 64; ++k) {
            const float2 a2 = *(const float2*)&xs[k * 34 + ty * 2];
            const float4 b4 = *(const float4*)&ws[k * 68 + tx * 4];
            acc[0][0] = fmaf(a2.x, b4.x, acc[0][0]);
            acc[0][1] = fmaf(a2.x, b4.y, acc[0][1]);
            acc[0][2] = fmaf(a2.x, b4.z, acc[0][2]);
            acc[0][3] = fmaf(a2.x, b4.w, acc[0][3]);
            acc[1][0] = fmaf(a2.y, b4.x, acc[1][0]);
            acc[1][1] = fmaf(a2.y, b4.y, acc[1][1]);
            acc[1][2] = fmaf(a2.y, b4.z, acc[1][2]);
            acc[1][3] = fmaf(a2.y, b4.w, acc[1][3]);
        }
        __syncthreads();
    }

    const float4 bb = *(const float4*)(Bv + tx * 4);
#pragma unroll
    for (int i = 0; i < 2; ++i) {
        acc[i][0] += bb.x; acc[i][1] += bb.y; acc[i][2] += bb.z; acc[i][3] += bb.w;
        float s = acc[i][0]*acc[i][0] + acc[i][1]*acc[i][1]
                + acc[i][2]*acc[i][2] + acc[i][3]*acc[i][3];
#pragma unroll
        for (int off = 1; off <= 8; off <<= 1)
            s += __shfl_xor(s, off, 64);
        const float inv = 1.0f / fmaxf(sqrtf(s), 1e-12f);

        unsigned short h[4], l[4];
#pragma unroll
        for (int j = 0; j < 4; ++j) {
            const float v = acc[i][j] * inv;
            h[j] = f2bf(v);
            l[j] = f2bf(v - bf2f(h[j]));
        }
        uint2 hp, lp;
        hp.x = (unsigned)h[0] | ((unsigned)h[1] << 16);
        hp.y = (unsigned)h[2] | ((unsigned)h[3] << 16);
        lp.x = (unsigned)l[0] | ((unsigned)l[1] << 16);
        lp.y = (unsigned)l[2] | ((unsigned)l[3] << 16);

        unsigned short* base = OUT + (size_t)(r0 + ty * 2 + i) * 192 + tx * 4;
        *(uint2*)(base)       = hp;
        *(uint2*)(base + 64)  = mat ? hp : lp;   // edge: hi ; sub: lo
        *(uint2*)(base + 128) = mat ? lp : hp;   // edge: lo ; sub: hi
    }
}

// ---------------------------------------------------------------------------
// Kernel F (v2): FUSED scores + entmax, register-budgeted.
//   Block = 1024 threads (16 waves) = 16 sub-rows x all 8192 edge cols.
//   Wave w owns edge cols [512w, 512w+512) = 32 MFMA tiles.
//   SWAPPED MFMA: D = mfma(A=edgeFrag, B=subFrag) so D col (lane&15) is the
//   SUB row -> each lane owns exactly ONE output row (row r0+li), 4
//   consecutive edge cols per acc (quad*4+reg).  tau/n/s1/s2 are scalars,
//   row-reduce is per-lane + shfl_xor(16,32); cross-wave via double-buffered
//   redS table, ONE barrier per entmax iteration, solve replicated per lane.
//   Scores held as 64 packed-fp16 VGPRs (zh[64]); budget ~120 VGPR -> fits
//   the 128-VGPR cap a 1024-thread block requires (r1 spilled at zh[128]).
//   fp16 quantization via __float2half_rn keeps r0/r1 numerics.
//   Output stores: float4v ext-vector (4 consecutive cols), nontemporal so
//   the 268 MB stream doesn't evict L2-resident edgeE for running blocks.
// ---------------------------------------------------------------------------
__global__ __launch_bounds__(1024, 4) void fused_score_entmax_kernel(
    const unsigned short* __restrict__ subE,
    const unsigned short* __restrict__ edgeE,
    const float* __restrict__ log_scale,
    float* __restrict__ out)
{
    const int t    = threadIdx.x;
    const int lane = t & 63;
    const int wid  = t >> 6;        // 0..15
    const int li   = lane & 15;     // sub-row owned by this lane
    const int quad = lane >> 4;     // 0..3
    const int r0   = blockIdx.x * 16;
    const int c0   = wid * 512;     // edge-col base of this wave

    __shared__ float4 redS[2][16][16];   // [buf][wave][row] = {n,s1,s2,-}

    // ---- B fragments: subE rows r0..r0+15, K=192 (all waves same 6 KB) ----
    short8 bf[6];
#pragma unroll
    for (int kk = 0; kk < 6; ++kk)
        bf[kk] = *(const short8*)(subE + (size_t)(r0 + li) * 192 + kk * 32 + quad * 8);

    float sc = expf(log_scale[0]);
    sc = fminf(fmaxf(sc, 0.5f), 20.0f);
    const float zs = sc * 0.5f;          // z = scores/2

    // ---- GEMM: 32 tiles/wave; acc[r] = (edge col c0+tp*16+quad*4+r, row li) ----
    unsigned int zh[64];                 // zh[tp*2+h]: cols quad*4+2h, +1 (packed fp16)

#pragma unroll
    for (int tp = 0; tp < 32; ++tp) {
        const unsigned short* ap = edgeE + (size_t)(c0 + tp * 16 + li) * 192 + quad * 8;
        float4v acc = (float4v){0.f, 0.f, 0.f, 0.f};
#pragma unroll
        for (int kk = 0; kk < 6; ++kk) {
            short8 af = *(const short8*)(ap + kk * 32);
            acc = __builtin_amdgcn_mfma_f32_16x16x32_bf16(af, bf[kk], acc, 0, 0, 0);
        }
        union { unsigned u; __half2 h2; } c01, c23;
        c01.h2.x = __float2half_rn(acc[0] * zs);
        c01.h2.y = __float2half_rn(acc[1] * zs);
        c23.h2.x = __float2half_rn(acc[2] * zs);
        c23.h2.y = __float2half_rn(acc[3] * zs);
        zh[tp * 2 + 0] = c01.u;
        zh[tp * 2 + 1] = c23.u;
    }

    // ---- row max -> tau0 = m - 1 (tau* is always in [m-1, m)) ----
    float m = -1e30f;
#pragma unroll
    for (int j = 0; j < 64; ++j) {
        union { unsigned u; __half2 h2; } cv; cv.u = zh[j];
        float2 f = __half22float2(cv.h2);
        m = fmaxf(m, fmaxf(f.x, f.y));
    }
    m = fmaxf(m, __shfl_xor(m, 16, 64));
    m = fmaxf(m, __shfl_xor(m, 32, 64));
    if (quad == 0) redS[0][wid][li] = (float4){m, 0.f, 0.f, 0.f};
    __syncthreads();
    {
        float mw = redS[0][quad * 4 + 0][li].x;
        mw = fmaxf(mw, redS[0][quad * 4 + 1][li].x);
        mw = fmaxf(mw, redS[0][quad * 4 + 2][li].x);
        mw = fmaxf(mw, redS[0][quad * 4 + 3][li].x);
        mw = fmaxf(mw, __shfl_xor(mw, 16, 64));
        mw = fmaxf(mw, __shfl_xor(mw, 32, 64));
        m = mw;
    }
    float tau = m - 1.0f;

    // ---- support-set iteration, exact quadratic solve, 1 barrier/iter ----
    int buf = 1;                         // iter 0 writes redS[1] (max used [0])
    for (int it = 0; it < ITERS; ++it) {
        float n = 0.f, s1 = 0.f, s2 = 0.f;
#pragma unroll
        for (int j = 0; j < 64; ++j) {
            union { unsigned u; __half2 h2; } cv; cv.u = zh[j];
            float2 f = __half22float2(cv.h2);
            {
                const bool  p  = f.x > tau;
                const float zm = p ? f.x : 0.f;
                n  += p ? 1.f : 0.f;
                s1 += zm;
                s2  = fmaf(zm, f.x, s2);
            }
            {
                const bool  p  = f.y > tau;
                const float zm = p ? f.y : 0.f;
                n  += p ? 1.f : 0.f;
                s1 += zm;
                s2  = fmaf(zm, f.y, s2);
            }
        }
        // combine the 4 lanes owning row li within this wave
        n  += __shfl_xor(n, 16, 64);  n  += __shfl_xor(n, 32, 64);
        s1 += __shfl_xor(s1, 16, 64); s1 += __shfl_xor(s1, 32, 64);
        s2 += __shfl_xor(s2, 16, 64); s2 += __shfl_xor(s2, 32, 64);
        if (quad == 0) redS[buf][wid][li] = (float4){n, s1, s2, 0.f};
        __syncthreads();

        // every lane gathers 4 waves' partials, combines quads via shfl
        float4 p0 = redS[buf][quad * 4 + 0][li];
        float4 p1 = redS[buf][quad * 4 + 1][li];
        float4 p2 = redS[buf][quad * 4 + 2][li];
        float4 p3 = redS[buf][quad * 4 + 3][li];
        float N  = p0.x + p1.x + p2.x + p3.x;
        float S1 = p0.y + p1.y + p2.y + p3.y;
        float S2 = p0.z + p1.z + p2.z + p3.z;
        N  += __shfl_xor(N, 16, 64);  N  += __shfl_xor(N, 32, 64);
        S1 += __shfl_xor(S1, 16, 64); S1 += __shfl_xor(S1, 32, 64);
        S2 += __shfl_xor(S2, 16, 64); S2 += __shfl_xor(S2, 32, 64);

        const float disc = S1 * S1 - N * (S2 - 1.0f);
        float tn;
        if (disc >= 0.0f) {
            tn = (S1 - sqrtf(disc)) / N;
        } else {
            const float g = S1 - N * tau;
            const float f = S2 - tau * (2.0f * S1 - N * tau);
            tn = tau + (f - 1.0f) / (2.0f * g);
        }
        const bool cf = (tn == tau);
        tau = tn;
        buf ^= 1;
        if (__all(cf)) break;            // identical in every wave
    }

    // ---- emit p = clip(z - tau, 0)^2, float4v nontemporal stores ----
    float* orow = out + (size_t)(r0 + li) * 8192 + c0;
#pragma unroll
    for (int tp = 0; tp < 32; ++tp) {
        union { unsigned u; __half2 h2; } c01, c23;
        c01.u = zh[tp * 2 + 0];
        c23.u = zh[tp * 2 + 1];
        float2 f01 = __half22float2(c01.h2);
        float2 f23 = __half22float2(c23.h2);
        float4v pv;
        float d;
        d = fmaxf(f01.x - tau, 0.f); pv.x = d * d;
        d = fmaxf(f01.y - tau, 0.f); pv.y = d * d;
        d = fmaxf(f23.x - tau, 0.f); pv.z = d * d;
        d = fmaxf(f23.y - tau, 0.f); pv.w = d * d;
        __builtin_nontemporal_store(pv, (float4v*)(orow + tp * 16 + quad * 4));
    }
}

// ---------------------------------------------------------------------------
extern "C" void kernel_launch(void* const* d_in, const int* in_sizes, int n_in,
                              void* d_out, int out_size, void* d_ws, size_t ws_size,
                              hipStream_t stream)
{
    const float* edge_repr = (const float*)d_in[0];
    const float* sub_repr  = (const float*)d_in[1];
    const float* W_sub     = (const float*)d_in[2];
    const float* b_sub     = (const float*)d_in[3];
    const float* W_edge    = (const float*)d_in[4];
    const float* b_edge    = (const float*)d_in[5];
    const float* log_scale = (const float*)d_in[6];
    float* out = (float*)d_out;

    unsigned short* subE  = (unsigned short*)d_ws;                 // 3 MB
    unsigned short* edgeE = subE + (size_t)8192 * 192;             // 3 MB

    proj_norm_kernel<<<dim3(256, 2), 256, 0, stream>>>(
        sub_repr, edge_repr, W_sub, b_sub, W_edge, b_edge, subE, edgeE);

    fused_score_entmax_kernel<<<dim3(512), 1024, 0, stream>>>(
        subE, edgeE, log_scale, out);
}